// Round 2
// baseline (2019.818 us; speedup 1.0000x reference)
//
#include <hip/hip_runtime.h>

typedef unsigned char u8;
typedef int i32x4 __attribute__((ext_vector_type(4)));
typedef int i32x16 __attribute__((ext_vector_type(16)));

#define C_DIM 640
#define HW_DIM 441
#define QN 75
#define SN 25
#define WAYS 5
#define MROWS 33075     // 75*441
#define MCH   128       // m rows per block
#define MBLK  259       // ceil(33075/128)
#define MPAD  33152     // MBLK*MCH
#define NWAY  2205      // 5*441
#define NPAD  2304      // 9*256
#define BN    256       // block n-tile
#define NT    9         // NPAD/BN
#define INV_Q2 (1.0f / 16129.0f)   // 1/127^2
#define NEGINF (-2147483647 - 1)

__device__ __forceinline__ void glds16(const void* g, void* l) {
  __builtin_amdgcn_global_load_lds(
      (__attribute__((address_space(1))) unsigned int*)g,
      (__attribute__((address_space(3))) unsigned int*)l, 16, 0, 0);
}

// 3-op sorted-top3 insert primitive: med3(v, hi, lo) == new lo-rank value.
__device__ __forceinline__ int med3i(int a, int b, int c) {
  int d;
  asm("v_med3_i32 %0, %1, %2, %3" : "=v"(d) : "v"(a), "v"(b), "v"(c));
  return d;
}

// ---------------------------------------------------------------------------
// Zero pad rows of A/B (int8 bytes) and the output accumulator.
// ---------------------------------------------------------------------------
__global__ void zero_pad(u8* __restrict__ A8, u8* __restrict__ S8,
                         float* __restrict__ out) {
  int i = blockIdx.x * 256 + threadIdx.x;
  if (i < 49280) {                                  // (MPAD-MROWS)*640 bytes
    A8[(size_t)MROWS * C_DIM + i] = 0;
    return;
  }
  i -= 49280;
  if (i < 316800) {                                 // 5*(NPAD-NWAY)*640 bytes
    const int w = i / 63360;
    const int r = i % 63360;
    S8[((size_t)w * NPAD + NWAY) * C_DIM + r] = 0;
    return;
  }
  i -= 316800;
  if (i < QN * WAYS) out[i] = 0.f;
}

// ---------------------------------------------------------------------------
// Normalize each (img, hw) descriptor over C, scale by 127, emit int8,
// transposed to [row][c] (c contiguous, 640 B/row). (unchanged)
// ---------------------------------------------------------------------------
__global__ __launch_bounds__(256)
void prep_norm_transpose(const float* __restrict__ src, u8* __restrict__ dst,
                         int support) {
  const int bid = blockIdx.x;
  const int img = bid / 7;
  const int mt = bid % 7;
  const int m0 = mt * 64;
  const int t = threadIdx.x;
  const int mloc = t & 63;
  const int cpart = t >> 6;                 // 0..3
  const int m = m0 + mloc;
  const int m_eff = (m < HW_DIM) ? m : (HW_DIM - 1);
  const float* base = src + (size_t)img * (C_DIM * HW_DIM);

  float ss = 0.f;
  const int c0 = cpart * 160;
  for (int c = c0; c < c0 + 160; ++c) {
    float v = base[(size_t)c * HW_DIM + m_eff];
    ss += v * v;
  }
  __shared__ float red[256];
  __shared__ float inv[64];
  red[t] = ss;
  __syncthreads();
  if (t < 64) {
    float s4 = red[t] + red[t + 64] + red[t + 128] + red[t + 192];
    inv[t] = rsqrtf(s4) * 127.0f;
  }
  __syncthreads();

  size_t drow0;
  if (support) {
    const int w = img / 5, shot = img % 5;
    drow0 = (size_t)w * NPAD + (size_t)shot * HW_DIM;
  } else {
    drow0 = (size_t)img * HW_DIM;
  }

  __shared__ __align__(16) u8 T[64][80];    // 64 data + 16 pad per row
  const float iv = inv[mloc];
  const int mw = t >> 2;
  const int cg = t & 3;
  const int m_out = m0 + mw;

  for (int ct = 0; ct < 10; ++ct) {
    int q[16];
#pragma unroll
    for (int ci = 0; ci < 16; ++ci) {
      const int c = ct * 64 + cpart * 16 + ci;
      q[ci] = __float2int_rn(base[(size_t)c * HW_DIM + m_eff] * iv);
    }
    __syncthreads();                        // previous tile fully consumed
    uint4 w;
    w.x = (q[0] & 255) | ((q[1] & 255) << 8) | ((q[2] & 255) << 16) | ((q[3] & 255) << 24);
    w.y = (q[4] & 255) | ((q[5] & 255) << 8) | ((q[6] & 255) << 16) | ((q[7] & 255) << 24);
    w.z = (q[8] & 255) | ((q[9] & 255) << 8) | ((q[10] & 255) << 16) | ((q[11] & 255) << 24);
    w.w = (q[12] & 255) | ((q[13] & 255) << 8) | ((q[14] & 255) << 16) | ((q[15] & 255) << 24);
    *(uint4*)&T[mloc][cpart * 16] = w;
    __syncthreads();
    if (m_out < HW_DIM) {
      const uint4 v = *(const uint4*)&T[mw][cg * 16];
      *(uint4*)(dst + (drow0 + m_out) * C_DIM + ct * 64 + cg * 16) = v;
    }
  }
}

// ---------------------------------------------------------------------------
// Fused cosine-sim GEMM (int8 mfma_i32_32x32x32) + per-row top-3 + sum.
// Round-9 structure (fixes R8's spill):
//  - Wave tile 64m x 128n kept (every B frag feeds 2 MFMAs -> LDS reads
//    per MFMA halved; block 128m x 256n halves staging writes too).
//  - A is NOT register-resident (that spilled: arch-VGPR cap is 256).
//    A is STREAMED per kt-phase from global (L2/L3-hot, re-read 9x),
//    software-pipelined one phase ahead in a ping-pong pair (64 VGPR).
//    Prefetch issued AFTER the MFMAs; the next __syncthreads vmcnt(0)
//    drain (already required for B's global_load_lds) hides it free.
//  - Arch VGPR ~210 (A pp 64 + top3 96 + B temps 16 + addr), acc 128 in
//    AGPRs -> no spill, 2 blocks/CU (LDS 64KB x2), 2 waves/SIMD.
// Grid: 5 ways * 259 m-chunks = 1295.
// ---------------------------------------------------------------------------
__global__ __launch_bounds__(256, 2)
void simtopk(const u8* __restrict__ A8, const u8* __restrict__ S8,
             float* __restrict__ out) {
  __shared__ __align__(16) u8 Bs[2][BN * 128];      // 64 KB B double buffer
  __shared__ float qsum[2];

  const int bid = blockIdx.x;
  const int way = bid / MBLK;
  const int mc = bid % MBLK;
  const int R0 = mc * MCH;
  const int tid = threadIdx.x;
  const int lane = tid & 63;
  const int wv = tid >> 6;                  // 0..3
  const int wm = (wv >> 1) * 64;            // wave m base: 0 / 64
  const int nh = wv & 1;                    // n-half: 0 / 1
  const int wnB = nh * 128;
  const int r5 = lane & 31;
  const int h = lane >> 5;                  // k-half selector

  if (tid < 2) qsum[tid] = 0.f;

  const u8* Sway = S8 + (size_t)way * NPAD * C_DIM;

  // ---- A row bases for this lane's two rows (r5, r5+32 within wave tile).
  const u8* Ar0 = A8 + (size_t)(R0 + wm + r5) * C_DIM + h * 16;
  const u8* Ar1 = Ar0 + 32 * C_DIM;

  // A ping-pong: phase kt uses (kt&1 ? aQ : aP); prefetch of kt+1 goes to
  // the other set, EXCEPT kt=4 whose successor (next nt's kt=0) uses aP
  // again -> self-target, safe because prefetch is issued after the MFMAs.
  i32x4 aP[8], aQ[8];
#pragma unroll
  for (int s = 0; s < 4; ++s) {             // prologue: kt=0 -> aP
    aP[s]     = *(const i32x4*)(Ar0 + s * 32);
    aP[4 + s] = *(const i32x4*)(Ar1 + s * 32);
  }

  // ---- B staging: strip = 8 rows x 128 B = 1 KB per instruction;
  // 32 strips per phase, 8 per wave. Source-side XOR swizzle.
  const unsigned brow =
      (unsigned)((lane >> 3) * 640 + (((lane & 7) ^ (lane >> 3)) * 16));
#pragma unroll
  for (int j = 0; j < 8; ++j) {             // prologue: phase 0 -> Bs[0]
    const int st = wv * 8 + j;
    glds16(Sway + (unsigned)st * (8 * 640) + brow, Bs[0] + st * 1024);
  }

  // ---- precomputed B-frag LDS offsets (b128, swizzled, conflict-free) ----
  int bBase[4], pqs[4];
#pragma unroll
  for (int ni = 0; ni < 4; ++ni)
    bBase[ni] = (wnB + ni * 32 + r5) * 128;
#pragma unroll
  for (int s = 0; s < 4; ++s)
    pqs[s] = ((2 * s + h) ^ (r5 & 7)) * 16;

  i32x16 acc[2][4];
#pragma unroll
  for (int mi = 0; mi < 2; ++mi)
#pragma unroll
    for (int ni = 0; ni < 4; ++ni)
#pragma unroll
      for (int g = 0; g < 16; ++g) acc[mi][ni][g] = 0;

  int t0[32], t1[32], t2[32];               // per-lane top-3, 32 row slots
#pragma unroll
  for (int r = 0; r < 32; ++r) { t0[r] = NEGINF; t1[r] = NEGINF; t2[r] = NEGINF; }

#define PHASE(KT, CUR, NXT)                                                   \
  {                                                                           \
    __syncthreads(); /* Bs[p] staged; Bs[p^1] free; A prefetch landed */      \
    const bool lastph = (nt == NT - 1) && ((KT) == 4);                        \
    const int kt1 = ((KT) == 4) ? 0 : ((KT) + 1);                             \
    if (!lastph) { /* B prefetch next phase -> Bs[p^1] */                     \
      const int nt1 = ((KT) == 4) ? nt + 1 : nt;                              \
      const unsigned off =                                                    \
          (unsigned)nt1 * (BN * C_DIM) + (unsigned)(kt1 * 128);               \
      _Pragma("unroll")                                                       \
      for (int j = 0; j < 8; ++j) {                                           \
        const int st = wv * 8 + j;                                            \
        glds16(Sway + (unsigned)st * (8 * 640) + brow + off,                  \
               Bs[p ^ 1] + st * 1024);                                        \
      }                                                                       \
    }                                                                         \
    const u8* Bp = Bs[p];                                                     \
    _Pragma("unroll")                                                         \
    for (int s = 0; s < 4; ++s) {                                             \
      const i32x4 av0 = CUR[s];                                               \
      const i32x4 av1 = CUR[4 + s];                                           \
      const i32x4 b0v = *(const i32x4*)(Bp + bBase[0] + pqs[s]);              \
      const i32x4 b1v = *(const i32x4*)(Bp + bBase[1] + pqs[s]);              \
      const i32x4 b2v = *(const i32x4*)(Bp + bBase[2] + pqs[s]);              \
      const i32x4 b3v = *(const i32x4*)(Bp + bBase[3] + pqs[s]);              \
      acc[0][0] = __builtin_amdgcn_mfma_i32_32x32x32_i8(av0, b0v, acc[0][0], 0, 0, 0); \
      acc[1][0] = __builtin_amdgcn_mfma_i32_32x32x32_i8(av1, b0v, acc[1][0], 0, 0, 0); \
      acc[0][1] = __builtin_amdgcn_mfma_i32_32x32x32_i8(av0, b1v, acc[0][1], 0, 0, 0); \
      acc[1][1] = __builtin_amdgcn_mfma_i32_32x32x32_i8(av1, b1v, acc[1][1], 0, 0, 0); \
      acc[0][2] = __builtin_amdgcn_mfma_i32_32x32x32_i8(av0, b2v, acc[0][2], 0, 0, 0); \
      acc[1][2] = __builtin_amdgcn_mfma_i32_32x32x32_i8(av1, b2v, acc[1][2], 0, 0, 0); \
      acc[0][3] = __builtin_amdgcn_mfma_i32_32x32x32_i8(av0, b3v, acc[0][3], 0, 0, 0); \
      acc[1][3] = __builtin_amdgcn_mfma_i32_32x32x32_i8(av1, b3v, acc[1][3], 0, 0, 0); \
    }                                                                         \
    if (!lastph) { /* A prefetch for kt1 (issued after MFMAs: WAR-safe) */    \
      _Pragma("unroll")                                                       \
      for (int s = 0; s < 4; ++s) {                                           \
        NXT[s]     = *(const i32x4*)(Ar0 + kt1 * 128 + s * 32);               \
        NXT[4 + s] = *(const i32x4*)(Ar1 + kt1 * 128 + s * 32);               \
      }                                                                       \
    }                                                                         \
    p ^= 1;                                                                   \
  }

  int p = 0;
  for (int nt = 0; nt < NT; ++nt) {
    PHASE(0, aP, aQ)
    PHASE(1, aQ, aP)
    PHASE(2, aP, aQ)
    PHASE(3, aQ, aP)
    PHASE(4, aP, aP)   // successor is next nt's kt=0, which uses aP

    // end of nt: branchless int top-3 insert (3 ops via med3), re-zero acc.
    // C/D 32x32: col = r5 (-> n), row = (g&3) + 8*(g>>2) + 4*h (+ wm + 32*mi).
    if (nt != NT - 1) {
#pragma unroll
      for (int mi = 0; mi < 2; ++mi)
#pragma unroll
        for (int ni = 0; ni < 4; ++ni)
#pragma unroll
          for (int g = 0; g < 16; ++g) {
            const int v = acc[mi][ni][g];
            const int r = mi * 16 + g;
            t2[r] = med3i(v, t1[r], t2[r]);
            t1[r] = med3i(v, t0[r], t1[r]);
            t0[r] = max(t0[r], v);
            acc[mi][ni][g] = 0;
          }
    } else {                                // last tile: mask pad columns
#pragma unroll
      for (int mi = 0; mi < 2; ++mi)
#pragma unroll
        for (int ni = 0; ni < 4; ++ni) {
          const int ncol = nt * BN + wnB + ni * 32 + r5;
          const bool bad = (ncol >= NWAY);
#pragma unroll
          for (int g = 0; g < 16; ++g) {
            int v = acc[mi][ni][g];
            if (bad) v = NEGINF;
            const int r = mi * 16 + g;
            t2[r] = med3i(v, t1[r], t2[r]);
            t1[r] = med3i(v, t0[r], t1[r]);
            t0[r] = max(t0[r], v);
          }
        }
    }
  }
#undef PHASE

  // ---- partial butterfly over column-lanes d=1,2 (stays in 32-lane half)
#pragma unroll
  for (int d = 1; d <= 2; d <<= 1) {
#pragma unroll
    for (int r = 0; r < 32; ++r) {
      const int o0 = __shfl_xor(t0[r], d);
      const int o1 = __shfl_xor(t1[r], d);
      const int o2 = __shfl_xor(t2[r], d);
      t2[r] = med3i(o0, t1[r], t2[r]);
      t1[r] = med3i(o0, t0[r], t1[r]);
      t0[r] = max(t0[r], o0);
      t2[r] = med3i(o1, t1[r], t2[r]);
      t1[r] = med3i(o1, t0[r], t1[r]);
      t0[r] = max(t0[r], o1);
      t2[r] = med3i(o2, t1[r], t2[r]);
      t1[r] = med3i(o2, t0[r], t1[r]);
      t0[r] = max(t0[r], o2);
    }
  }

  // dump 32 partials/row-slot (2 nh x 8 col-groups = 16 grp) to LDS over Bs.
  // XOR swizzle (row ^ (grp&7)) keeps write/read patterns conflict-light.
  __syncthreads();                          // all B-tile reads complete
  int* part = (int*)&Bs[0][0];              // part[grp][row][4] : 32 KB
  if ((r5 & 3) == 0) {
    const int grp = nh * 8 + (r5 >> 2);     // 0..15
#pragma unroll
    for (int r = 0; r < 32; ++r) {
      const int mi = r >> 4;
      const int g = r & 15;
      const int row_local = wm + mi * 32 + (g & 3) + 8 * (g >> 2) + 4 * h;
      i32x4 v;
      v[0] = t0[r]; v[1] = t1[r]; v[2] = t2[r]; v[3] = NEGINF;
      *(i32x4*)&part[(grp * MCH + (row_local ^ (grp & 7))) * 4] = v;
    }
  }
  __syncthreads();
  if (tid < MCH) {
    const int grow = R0 + tid;
    if (grow < MROWS) {
      int a0_ = NEGINF, a1_ = NEGINF, a2_ = NEGINF;
#pragma unroll 4
      for (int g = 0; g < 16; ++g) {
        const i32x4 v = *(const i32x4*)&part[(g * MCH + (tid ^ (g & 7))) * 4];
        a2_ = med3i(v[0], a1_, a2_); a1_ = med3i(v[0], a0_, a1_); a0_ = max(a0_, v[0]);
        a2_ = med3i(v[1], a1_, a2_); a1_ = med3i(v[1], a0_, a1_); a0_ = max(a0_, v[1]);
        a2_ = med3i(v[2], a1_, a2_); a1_ = med3i(v[2], a0_, a1_); a0_ = max(a0_, v[2]);
      }
      const float rs = (float)(a0_ + a1_ + a2_) * INV_Q2;
      const int qq = grow / HW_DIM;
      atomicAdd(&qsum[qq - (R0 / HW_DIM)], rs);     // block spans <= 2 q's
    }
  }
  __syncthreads();
  if (tid < 2) {
    const int qq = R0 / HW_DIM + tid;
    if (qq < QN) atomicAdd(out + qq * WAYS + way, qsum[tid]);
  }
}

// ---------------------------------------------------------------------------
extern "C" void kernel_launch(void* const* d_in, const int* in_sizes, int n_in,
                              void* d_out, int out_size, void* d_ws, size_t ws_size,
                              hipStream_t stream) {
  const float* x1 = (const float*)d_in[0];
  const float* x2 = (const float*)d_in[1];
  float* out = (float*)d_out;
  u8* A8 = (u8*)d_ws;                                        // MPAD x 640 i8
  u8* S8 = (u8*)d_ws + (size_t)MPAD * C_DIM;                 // 5 x NPAD x 640

  hipLaunchKernelGGL(zero_pad, dim3(1432), dim3(256), 0, stream, A8, S8, out);
  hipLaunchKernelGGL(prep_norm_transpose, dim3(QN * 7), dim3(256), 0, stream,
                     x1, A8, 0);
  hipLaunchKernelGGL(prep_norm_transpose, dim3(SN * 7), dim3(256), 0, stream,
                     x2, S8, 1);
  hipLaunchKernelGGL(simtopk, dim3(WAYS * MBLK), dim3(256), 0, stream,
                     A8, S8, out);
}

// Round 3
// 2018.844 us; speedup vs baseline: 1.0005x; 1.0005x over previous
//
#include <hip/hip_runtime.h>

typedef unsigned char u8;
typedef int i32x4 __attribute__((ext_vector_type(4)));
typedef int i32x16 __attribute__((ext_vector_type(16)));

#define C_DIM 640
#define HW_DIM 441
#define QN 75
#define SN 25
#define WAYS 5
#define MROWS 33075     // 75*441
#define MCH   128       // m rows per block
#define MBLK  259       // ceil(33075/128)
#define MPAD  33152     // MBLK*MCH
#define NWAY  2205      // 5*441
#define NPAD  2304      // 9*256
#define BN    256       // block n-tile
#define NT    9         // NPAD/BN
#define INV_Q2 (1.0f / 16129.0f)   // 1/127^2
#define NEGINF (-2147483647 - 1)

__device__ __forceinline__ void glds16(const void* g, void* l) {
  __builtin_amdgcn_global_load_lds(
      (__attribute__((address_space(1))) unsigned int*)g,
      (__attribute__((address_space(3))) unsigned int*)l, 16, 0, 0);
}

// 3-op sorted-top3 insert primitive: med3(v, hi, lo) == new lo-rank value.
__device__ __forceinline__ int med3i(int a, int b, int c) {
  int d;
  asm("v_med3_i32 %0, %1, %2, %3" : "=v"(d) : "v"(a), "v"(b), "v"(c));
  return d;
}

// ---------------------------------------------------------------------------
// Zero pad rows of A/B (int8 bytes) and the output accumulator.
// ---------------------------------------------------------------------------
__global__ void zero_pad(u8* __restrict__ A8, u8* __restrict__ S8,
                         float* __restrict__ out) {
  int i = blockIdx.x * 256 + threadIdx.x;
  if (i < 49280) {                                  // (MPAD-MROWS)*640 bytes
    A8[(size_t)MROWS * C_DIM + i] = 0;
    return;
  }
  i -= 49280;
  if (i < 316800) {                                 // 5*(NPAD-NWAY)*640 bytes
    const int w = i / 63360;
    const int r = i % 63360;
    S8[((size_t)w * NPAD + NWAY) * C_DIM + r] = 0;
    return;
  }
  i -= 316800;
  if (i < QN * WAYS) out[i] = 0.f;
}

// ---------------------------------------------------------------------------
// Normalize each (img, hw) descriptor over C, scale by 127, emit int8,
// transposed to [row][c] (c contiguous, 640 B/row). (unchanged)
// ---------------------------------------------------------------------------
__global__ __launch_bounds__(256)
void prep_norm_transpose(const float* __restrict__ src, u8* __restrict__ dst,
                         int support) {
  const int bid = blockIdx.x;
  const int img = bid / 7;
  const int mt = bid % 7;
  const int m0 = mt * 64;
  const int t = threadIdx.x;
  const int mloc = t & 63;
  const int cpart = t >> 6;                 // 0..3
  const int m = m0 + mloc;
  const int m_eff = (m < HW_DIM) ? m : (HW_DIM - 1);
  const float* base = src + (size_t)img * (C_DIM * HW_DIM);

  float ss = 0.f;
  const int c0 = cpart * 160;
  for (int c = c0; c < c0 + 160; ++c) {
    float v = base[(size_t)c * HW_DIM + m_eff];
    ss += v * v;
  }
  __shared__ float red[256];
  __shared__ float inv[64];
  red[t] = ss;
  __syncthreads();
  if (t < 64) {
    float s4 = red[t] + red[t + 64] + red[t + 128] + red[t + 192];
    inv[t] = rsqrtf(s4) * 127.0f;
  }
  __syncthreads();

  size_t drow0;
  if (support) {
    const int w = img / 5, shot = img % 5;
    drow0 = (size_t)w * NPAD + (size_t)shot * HW_DIM;
  } else {
    drow0 = (size_t)img * HW_DIM;
  }

  __shared__ __align__(16) u8 T[64][80];    // 64 data + 16 pad per row
  const float iv = inv[mloc];
  const int mw = t >> 2;
  const int cg = t & 3;
  const int m_out = m0 + mw;

  for (int ct = 0; ct < 10; ++ct) {
    int q[16];
#pragma unroll
    for (int ci = 0; ci < 16; ++ci) {
      const int c = ct * 64 + cpart * 16 + ci;
      q[ci] = __float2int_rn(base[(size_t)c * HW_DIM + m_eff] * iv);
    }
    __syncthreads();                        // previous tile fully consumed
    uint4 w;
    w.x = (q[0] & 255) | ((q[1] & 255) << 8) | ((q[2] & 255) << 16) | ((q[3] & 255) << 24);
    w.y = (q[4] & 255) | ((q[5] & 255) << 8) | ((q[6] & 255) << 16) | ((q[7] & 255) << 24);
    w.z = (q[8] & 255) | ((q[9] & 255) << 8) | ((q[10] & 255) << 16) | ((q[11] & 255) << 24);
    w.w = (q[12] & 255) | ((q[13] & 255) << 8) | ((q[14] & 255) << 16) | ((q[15] & 255) << 24);
    *(uint4*)&T[mloc][cpart * 16] = w;
    __syncthreads();
    if (m_out < HW_DIM) {
      const uint4 v = *(const uint4*)&T[mw][cg * 16];
      *(uint4*)(dst + (drow0 + m_out) * C_DIM + ct * 64 + cg * 16) = v;
    }
  }
}

// ---------------------------------------------------------------------------
// Fused cosine-sim GEMM (int8 mfma_i32_32x32x32) + per-row top-3 + sum.
// Round-10 structure (fixes R9's occupancy bug):
//  - Wave tile 64m x 128n: every B frag read from LDS feeds 2 MFMAs.
//  - A streamed per kt-phase from L2/L3, ping-pong pair (64 VGPR).
//  - __launch_bounds__(256, 1): the per-SIMD unified RF is 512 regs.
//    This wave needs ~210 arch VGPR + 128 AGPR acc ~= 340 unified ->
//    exactly ONE wave/SIMD. (256,2) capped arch at 128 and spilled
//    2.8 GB of scratch (R9 post-mortem). One block/CU is correct here.
//  - A prefetch issued BEFORE the MFMA burst when it targets the other
//    ping-pong buffer (kt != 4) so its latency hides under ~1100 cyc of
//    MFMA; kt==4 self-targets aP so it must stay after the MFMAs.
// Per-phase model @1 block/CU: MFMA ~1170 cyc, LDS ~1070 cyc -> compute-
// bound for the first time.
// Grid: 5 ways * 259 m-chunks = 1295.
// ---------------------------------------------------------------------------
__global__ __launch_bounds__(256, 1)
void simtopk(const u8* __restrict__ A8, const u8* __restrict__ S8,
             float* __restrict__ out) {
  __shared__ __align__(16) u8 Bs[2][BN * 128];      // 64 KB B double buffer
  __shared__ float qsum[2];

  const int bid = blockIdx.x;
  const int way = bid / MBLK;
  const int mc = bid % MBLK;
  const int R0 = mc * MCH;
  const int tid = threadIdx.x;
  const int lane = tid & 63;
  const int wv = tid >> 6;                  // 0..3
  const int wm = (wv >> 1) * 64;            // wave m base: 0 / 64
  const int nh = wv & 1;                    // n-half: 0 / 1
  const int wnB = nh * 128;
  const int r5 = lane & 31;
  const int h = lane >> 5;                  // k-half selector

  if (tid < 2) qsum[tid] = 0.f;

  const u8* Sway = S8 + (size_t)way * NPAD * C_DIM;

  // ---- A row bases for this lane's two rows (r5, r5+32 within wave tile).
  const u8* Ar0 = A8 + (size_t)(R0 + wm + r5) * C_DIM + h * 16;
  const u8* Ar1 = Ar0 + 32 * C_DIM;

  // A ping-pong: phase kt uses (kt&1 ? aQ : aP).
  i32x4 aP[8], aQ[8];
#pragma unroll
  for (int s = 0; s < 4; ++s) {             // prologue: kt=0 -> aP
    aP[s]     = *(const i32x4*)(Ar0 + s * 32);
    aP[4 + s] = *(const i32x4*)(Ar1 + s * 32);
  }

  // ---- B staging: strip = 8 rows x 128 B = 1 KB per instruction;
  // 32 strips per phase, 8 per wave. Source-side XOR swizzle.
  const unsigned brow =
      (unsigned)((lane >> 3) * 640 + (((lane & 7) ^ (lane >> 3)) * 16));
#pragma unroll
  for (int j = 0; j < 8; ++j) {             // prologue: phase 0 -> Bs[0]
    const int st = wv * 8 + j;
    glds16(Sway + (unsigned)st * (8 * 640) + brow, Bs[0] + st * 1024);
  }

  // ---- precomputed B-frag LDS offsets (b128, swizzled, conflict-free) ----
  int bBase[4], pqs[4];
#pragma unroll
  for (int ni = 0; ni < 4; ++ni)
    bBase[ni] = (wnB + ni * 32 + r5) * 128;
#pragma unroll
  for (int s = 0; s < 4; ++s)
    pqs[s] = ((2 * s + h) ^ (r5 & 7)) * 16;

  i32x16 acc[2][4];
#pragma unroll
  for (int mi = 0; mi < 2; ++mi)
#pragma unroll
    for (int ni = 0; ni < 4; ++ni)
#pragma unroll
      for (int g = 0; g < 16; ++g) acc[mi][ni][g] = 0;

  int t0[32], t1[32], t2[32];               // per-lane top-3, 32 row slots
#pragma unroll
  for (int r = 0; r < 32; ++r) { t0[r] = NEGINF; t1[r] = NEGINF; t2[r] = NEGINF; }

// PRE: A-prefetch before MFMAs (targets other buffer). POST: after (kt==4).
#define PHASE(KT, CUR, NXT, PRE)                                              \
  {                                                                           \
    __syncthreads(); /* Bs[p] staged; Bs[p^1] free; A prefetch landed */      \
    const bool lastph = (nt == NT - 1) && ((KT) == 4);                        \
    const int kt1 = ((KT) == 4) ? 0 : ((KT) + 1);                             \
    if (!lastph) { /* B prefetch next phase -> Bs[p^1] */                     \
      const int nt1 = ((KT) == 4) ? nt + 1 : nt;                              \
      const unsigned off =                                                    \
          (unsigned)nt1 * (BN * C_DIM) + (unsigned)(kt1 * 128);               \
      _Pragma("unroll")                                                       \
      for (int j = 0; j < 8; ++j) {                                           \
        const int st = wv * 8 + j;                                            \
        glds16(Sway + (unsigned)st * (8 * 640) + brow + off,                  \
               Bs[p ^ 1] + st * 1024);                                        \
      }                                                                       \
    }                                                                         \
    if ((PRE) && !lastph) {                                                   \
      _Pragma("unroll")                                                       \
      for (int s = 0; s < 4; ++s) {                                           \
        NXT[s]     = *(const i32x4*)(Ar0 + kt1 * 128 + s * 32);               \
        NXT[4 + s] = *(const i32x4*)(Ar1 + kt1 * 128 + s * 32);               \
      }                                                                       \
    }                                                                         \
    const u8* Bp = Bs[p];                                                     \
    _Pragma("unroll")                                                         \
    for (int s = 0; s < 4; ++s) {                                             \
      const i32x4 av0 = CUR[s];                                               \
      const i32x4 av1 = CUR[4 + s];                                           \
      const i32x4 b0v = *(const i32x4*)(Bp + bBase[0] + pqs[s]);              \
      const i32x4 b1v = *(const i32x4*)(Bp + bBase[1] + pqs[s]);              \
      const i32x4 b2v = *(const i32x4*)(Bp + bBase[2] + pqs[s]);              \
      const i32x4 b3v = *(const i32x4*)(Bp + bBase[3] + pqs[s]);              \
      acc[0][0] = __builtin_amdgcn_mfma_i32_32x32x32_i8(av0, b0v, acc[0][0], 0, 0, 0); \
      acc[1][0] = __builtin_amdgcn_mfma_i32_32x32x32_i8(av1, b0v, acc[1][0], 0, 0, 0); \
      acc[0][1] = __builtin_amdgcn_mfma_i32_32x32x32_i8(av0, b1v, acc[0][1], 0, 0, 0); \
      acc[1][1] = __builtin_amdgcn_mfma_i32_32x32x32_i8(av1, b1v, acc[1][1], 0, 0, 0); \
      acc[0][2] = __builtin_amdgcn_mfma_i32_32x32x32_i8(av0, b2v, acc[0][2], 0, 0, 0); \
      acc[1][2] = __builtin_amdgcn_mfma_i32_32x32x32_i8(av1, b2v, acc[1][2], 0, 0, 0); \
      acc[0][3] = __builtin_amdgcn_mfma_i32_32x32x32_i8(av0, b3v, acc[0][3], 0, 0, 0); \
      acc[1][3] = __builtin_amdgcn_mfma_i32_32x32x32_i8(av1, b3v, acc[1][3], 0, 0, 0); \
    }                                                                         \
    if (!(PRE) && !lastph) { /* kt==4: self-target aP, must follow MFMAs */   \
      _Pragma("unroll")                                                       \
      for (int s = 0; s < 4; ++s) {                                           \
        NXT[s]     = *(const i32x4*)(Ar0 + kt1 * 128 + s * 32);               \
        NXT[4 + s] = *(const i32x4*)(Ar1 + kt1 * 128 + s * 32);               \
      }                                                                       \
    }                                                                         \
    p ^= 1;                                                                   \
  }

  int p = 0;
  for (int nt = 0; nt < NT; ++nt) {
    PHASE(0, aP, aQ, 1)
    PHASE(1, aQ, aP, 1)
    PHASE(2, aP, aQ, 1)
    PHASE(3, aQ, aP, 1)
    PHASE(4, aP, aP, 0)  // successor is next nt's kt=0, which uses aP

    // end of nt: branchless int top-3 insert (3 ops via med3), re-zero acc.
    // C/D 32x32: col = r5 (-> n), row = (g&3) + 8*(g>>2) + 4*h (+ wm + 32*mi).
    if (nt != NT - 1) {
#pragma unroll
      for (int mi = 0; mi < 2; ++mi)
#pragma unroll
        for (int ni = 0; ni < 4; ++ni)
#pragma unroll
          for (int g = 0; g < 16; ++g) {
            const int v = acc[mi][ni][g];
            const int r = mi * 16 + g;
            t2[r] = med3i(v, t1[r], t2[r]);
            t1[r] = med3i(v, t0[r], t1[r]);
            t0[r] = max(t0[r], v);
            acc[mi][ni][g] = 0;
          }
    } else {                                // last tile: mask pad columns
#pragma unroll
      for (int mi = 0; mi < 2; ++mi)
#pragma unroll
        for (int ni = 0; ni < 4; ++ni) {
          const int ncol = nt * BN + wnB + ni * 32 + r5;
          const bool bad = (ncol >= NWAY);
#pragma unroll
          for (int g = 0; g < 16; ++g) {
            int v = acc[mi][ni][g];
            if (bad) v = NEGINF;
            const int r = mi * 16 + g;
            t2[r] = med3i(v, t1[r], t2[r]);
            t1[r] = med3i(v, t0[r], t1[r]);
            t0[r] = max(t0[r], v);
          }
        }
    }
  }
#undef PHASE

  // ---- partial butterfly over column-lanes d=1,2 (stays in 32-lane half)
#pragma unroll
  for (int d = 1; d <= 2; d <<= 1) {
#pragma unroll
    for (int r = 0; r < 32; ++r) {
      const int o0 = __shfl_xor(t0[r], d);
      const int o1 = __shfl_xor(t1[r], d);
      const int o2 = __shfl_xor(t2[r], d);
      t2[r] = med3i(o0, t1[r], t2[r]);
      t1[r] = med3i(o0, t0[r], t1[r]);
      t0[r] = max(t0[r], o0);
      t2[r] = med3i(o1, t1[r], t2[r]);
      t1[r] = med3i(o1, t0[r], t1[r]);
      t0[r] = max(t0[r], o1);
      t2[r] = med3i(o2, t1[r], t2[r]);
      t1[r] = med3i(o2, t0[r], t1[r]);
      t0[r] = max(t0[r], o2);
    }
  }

  // dump 32 partials/row-slot (2 nh x 8 col-groups = 16 grp) to LDS over Bs.
  // XOR swizzle (row ^ (grp&7)) keeps write/read patterns conflict-light.
  __syncthreads();                          // all B-tile reads complete
  int* part = (int*)&Bs[0][0];              // part[grp][row][4] : 32 KB
  if ((r5 & 3) == 0) {
    const int grp = nh * 8 + (r5 >> 2);     // 0..15
#pragma unroll
    for (int r = 0; r < 32; ++r) {
      const int mi = r >> 4;
      const int g = r & 15;
      const int row_local = wm + mi * 32 + (g & 3) + 8 * (g >> 2) + 4 * h;
      i32x4 v;
      v[0] = t0[r]; v[1] = t1[r]; v[2] = t2[r]; v[3] = NEGINF;
      *(i32x4*)&part[(grp * MCH + (row_local ^ (grp & 7))) * 4] = v;
    }
  }
  __syncthreads();
  if (tid < MCH) {
    const int grow = R0 + tid;
    if (grow < MROWS) {
      int a0_ = NEGINF, a1_ = NEGINF, a2_ = NEGINF;
#pragma unroll 4
      for (int g = 0; g < 16; ++g) {
        const i32x4 v = *(const i32x4*)&part[(g * MCH + (tid ^ (g & 7))) * 4];
        a2_ = med3i(v[0], a1_, a2_); a1_ = med3i(v[0], a0_, a1_); a0_ = max(a0_, v[0]);
        a2_ = med3i(v[1], a1_, a2_); a1_ = med3i(v[1], a0_, a1_); a0_ = max(a0_, v[1]);
        a2_ = med3i(v[2], a1_, a2_); a1_ = med3i(v[2], a0_, a1_); a0_ = max(a0_, v[2]);
      }
      const float rs = (float)(a0_ + a1_ + a2_) * INV_Q2;
      const int qq = grow / HW_DIM;
      atomicAdd(&qsum[qq - (R0 / HW_DIM)], rs);     // block spans <= 2 q's
    }
  }
  __syncthreads();
  if (tid < 2) {
    const int qq = R0 / HW_DIM + tid;
    if (qq < QN) atomicAdd(out + qq * WAYS + way, qsum[tid]);
  }
}

// ---------------------------------------------------------------------------
extern "C" void kernel_launch(void* const* d_in, const int* in_sizes, int n_in,
                              void* d_out, int out_size, void* d_ws, size_t ws_size,
                              hipStream_t stream) {
  const float* x1 = (const float*)d_in[0];
  const float* x2 = (const float*)d_in[1];
  float* out = (float*)d_out;
  u8* A8 = (u8*)d_ws;                                        // MPAD x 640 i8
  u8* S8 = (u8*)d_ws + (size_t)MPAD * C_DIM;                 // 5 x NPAD x 640

  hipLaunchKernelGGL(zero_pad, dim3(1432), dim3(256), 0, stream, A8, S8, out);
  hipLaunchKernelGGL(prep_norm_transpose, dim3(QN * 7), dim3(256), 0, stream,
                     x1, A8, 0);
  hipLaunchKernelGGL(prep_norm_transpose, dim3(SN * 7), dim3(256), 0, stream,
                     x2, S8, 1);
  hipLaunchKernelGGL(simtopk, dim3(WAYS * MBLK), dim3(256), 0, stream,
                     A8, S8, out);
}

// Round 4
// 897.046 us; speedup vs baseline: 2.2516x; 2.2505x over previous
//
#include <hip/hip_runtime.h>

typedef unsigned char u8;
typedef int i32x4 __attribute__((ext_vector_type(4)));
typedef int i32x16 __attribute__((ext_vector_type(16)));

#define C_DIM 640
#define HW_DIM 441
#define QN 75
#define SN 25
#define WAYS 5
#define MROWS 33075     // 75*441
#define MCH   128       // m rows per block
#define MBLK  259       // ceil(33075/128)
#define MPAD  33152     // MBLK*MCH
#define NWAY  2205      // 5*441
#define NPAD  2304      // 18*128
#define BN    128       // block n-tile
#define NT    18        // NPAD/BN
#define INV_Q2 (1.0f / 16129.0f)   // 1/127^2
#define NEGINF (-2147483647 - 1)

__device__ __forceinline__ void glds16(const void* g, void* l) {
  __builtin_amdgcn_global_load_lds(
      (__attribute__((address_space(1))) unsigned int*)g,
      (__attribute__((address_space(3))) unsigned int*)l, 16, 0, 0);
}

// 3-op sorted-top3 insert primitive: med3(v, hi, lo) == new lo-rank value.
__device__ __forceinline__ int med3i(int a, int b, int c) {
  int d;
  asm("v_med3_i32 %0, %1, %2, %3" : "=v"(d) : "v"(a), "v"(b), "v"(c));
  return d;
}

// ---------------------------------------------------------------------------
// Zero pad rows of A/B (int8 bytes) and the output accumulator.
// ---------------------------------------------------------------------------
__global__ void zero_pad(u8* __restrict__ A8, u8* __restrict__ S8,
                         float* __restrict__ out) {
  int i = blockIdx.x * 256 + threadIdx.x;
  if (i < 49280) {                                  // (MPAD-MROWS)*640 bytes
    A8[(size_t)MROWS * C_DIM + i] = 0;
    return;
  }
  i -= 49280;
  if (i < 316800) {                                 // 5*(NPAD-NWAY)*640 bytes
    const int w = i / 63360;
    const int r = i % 63360;
    S8[((size_t)w * NPAD + NWAY) * C_DIM + r] = 0;
    return;
  }
  i -= 316800;
  if (i < QN * WAYS) out[i] = 0.f;
}

// ---------------------------------------------------------------------------
// Normalize each (img, hw) descriptor over C, scale by 127, emit int8,
// transposed to [row][c] (c contiguous, 640 B/row). (unchanged)
// ---------------------------------------------------------------------------
__global__ __launch_bounds__(256)
void prep_norm_transpose(const float* __restrict__ src, u8* __restrict__ dst,
                         int support) {
  const int bid = blockIdx.x;
  const int img = bid / 7;
  const int mt = bid % 7;
  const int m0 = mt * 64;
  const int t = threadIdx.x;
  const int mloc = t & 63;
  const int cpart = t >> 6;                 // 0..3
  const int m = m0 + mloc;
  const int m_eff = (m < HW_DIM) ? m : (HW_DIM - 1);
  const float* base = src + (size_t)img * (C_DIM * HW_DIM);

  float ss = 0.f;
  const int c0 = cpart * 160;
  for (int c = c0; c < c0 + 160; ++c) {
    float v = base[(size_t)c * HW_DIM + m_eff];
    ss += v * v;
  }
  __shared__ float red[256];
  __shared__ float inv[64];
  red[t] = ss;
  __syncthreads();
  if (t < 64) {
    float s4 = red[t] + red[t + 64] + red[t + 128] + red[t + 192];
    inv[t] = rsqrtf(s4) * 127.0f;
  }
  __syncthreads();

  size_t drow0;
  if (support) {
    const int w = img / 5, shot = img % 5;
    drow0 = (size_t)w * NPAD + (size_t)shot * HW_DIM;
  } else {
    drow0 = (size_t)img * HW_DIM;
  }

  __shared__ __align__(16) u8 T[64][80];    // 64 data + 16 pad per row
  const float iv = inv[mloc];
  const int mw = t >> 2;
  const int cg = t & 3;
  const int m_out = m0 + mw;

  for (int ct = 0; ct < 10; ++ct) {
    int q[16];
#pragma unroll
    for (int ci = 0; ci < 16; ++ci) {
      const int c = ct * 64 + cpart * 16 + ci;
      q[ci] = __float2int_rn(base[(size_t)c * HW_DIM + m_eff] * iv);
    }
    __syncthreads();                        // previous tile fully consumed
    uint4 w;
    w.x = (q[0] & 255) | ((q[1] & 255) << 8) | ((q[2] & 255) << 16) | ((q[3] & 255) << 24);
    w.y = (q[4] & 255) | ((q[5] & 255) << 8) | ((q[6] & 255) << 16) | ((q[7] & 255) << 24);
    w.z = (q[8] & 255) | ((q[9] & 255) << 8) | ((q[10] & 255) << 16) | ((q[11] & 255) << 24);
    w.w = (q[12] & 255) | ((q[13] & 255) << 8) | ((q[14] & 255) << 16) | ((q[15] & 255) << 24);
    *(uint4*)&T[mloc][cpart * 16] = w;
    __syncthreads();
    if (m_out < HW_DIM) {
      const uint4 v = *(const uint4*)&T[mw][cg * 16];
      *(uint4*)(dst + (drow0 + m_out) * C_DIM + ct * 64 + cg * 16) = v;
    }
  }
}

// ---------------------------------------------------------------------------
// Fused cosine-sim GEMM (int8 mfma_i32_32x32x32) + per-row top-3 + sum.
// Round-11 structure (fits the 256 arch-VGPR partition BY DESIGN):
//  - R1-R3 lesson: MFMA acc stays in VGPR-form on gfx950; everything
//    (acc + top3 + A stream + temps) must fit 256 arch VGPRs or it
//    scratch-spills (GBs of traffic). 64m x 128n needed ~290 -> dead.
//  - Wave tile 64m x 64n: acc = 2x2 i32x16 = 64 regs. Each B frag still
//    feeds 2 MFMAs (2 m-halves in-wave) -> LDS reads/MFMA halved vs R0;
//    stage writes/MFMA also halved (BN bytes per 64-MFMA phase).
//  - Budget: acc 64 + top3 96 + A ping-pong 64 + temps ~30 = ~254.
//    launch_bounds(256,1) -> hard budget 512, no spill possible.
//  - Block 128m x 128n (4 waves, 2m x 2n), BN=128, NT=18, 90 phases.
//  - Per-CU phase model: MFMA 586 cyc, LDS 48 KB ~ 546 cyc -> compute-
//    bound; top-3 insert (per nt) overlaps next phase's staging drain.
// Grid: 5 ways * 259 m-chunks = 1295.
// ---------------------------------------------------------------------------
__global__ __launch_bounds__(256, 1)
void simtopk(const u8* __restrict__ A8, const u8* __restrict__ S8,
             float* __restrict__ out) {
  __shared__ __align__(16) u8 Bs[2][BN * 128];      // 32 KB B double buffer
  __shared__ float qsum[2];

  const int bid = blockIdx.x;
  const int way = bid / MBLK;
  const int mc = bid % MBLK;
  const int R0 = mc * MCH;
  const int tid = threadIdx.x;
  const int lane = tid & 63;
  const int wv = tid >> 6;                  // 0..3
  const int wm = (wv >> 1) * 64;            // wave m base: 0 / 64
  const int nh = wv & 1;                    // n-half: 0 / 1
  const int wnB = nh * 64;                  // wave n base within BN=128
  const int r5 = lane & 31;
  const int h = lane >> 5;                  // k-half selector

  if (tid < 2) qsum[tid] = 0.f;

  const u8* Sway = S8 + (size_t)way * NPAD * C_DIM;

  // ---- A row bases for this lane's two rows (r5, r5+32 within wave tile).
  const u8* Ar0 = A8 + (size_t)(R0 + wm + r5) * C_DIM + h * 16;
  const u8* Ar1 = Ar0 + 32 * C_DIM;

  // A ping-pong: phase kt uses (kt&1 ? aQ : aP).
  i32x4 aP[8], aQ[8];
#pragma unroll
  for (int s = 0; s < 4; ++s) {             // prologue: kt=0 -> aP
    aP[s]     = *(const i32x4*)(Ar0 + s * 32);
    aP[4 + s] = *(const i32x4*)(Ar1 + s * 32);
  }

  // ---- B staging: strip = 8 rows x 128 B = 1 KB per instruction;
  // 16 strips per phase (BN=128), 4 per wave. Source-side XOR swizzle.
  const unsigned brow =
      (unsigned)((lane >> 3) * 640 + (((lane & 7) ^ (lane >> 3)) * 16));
#pragma unroll
  for (int j = 0; j < 4; ++j) {             // prologue: phase 0 -> Bs[0]
    const int st = wv * 4 + j;
    glds16(Sway + (unsigned)st * (8 * 640) + brow, Bs[0] + st * 1024);
  }

  // ---- precomputed B-frag LDS offsets (b128, swizzled, conflict-free) ----
  int bBase[2], pqs[4];
#pragma unroll
  for (int ni = 0; ni < 2; ++ni)
    bBase[ni] = (wnB + ni * 32 + r5) * 128;
#pragma unroll
  for (int s = 0; s < 4; ++s)
    pqs[s] = ((2 * s + h) ^ (r5 & 7)) * 16;

  i32x16 acc[2][2];
#pragma unroll
  for (int mi = 0; mi < 2; ++mi)
#pragma unroll
    for (int ni = 0; ni < 2; ++ni)
#pragma unroll
      for (int g = 0; g < 16; ++g) acc[mi][ni][g] = 0;

  int t0[32], t1[32], t2[32];               // per-lane top-3, 32 row slots
#pragma unroll
  for (int r = 0; r < 32; ++r) { t0[r] = NEGINF; t1[r] = NEGINF; t2[r] = NEGINF; }

// PRE: A-prefetch before MFMAs (targets other buffer). POST: after (kt==4).
#define PHASE(KT, CUR, NXT, PRE)                                              \
  {                                                                           \
    __syncthreads(); /* Bs[p] staged; Bs[p^1] free; A prefetch landed */      \
    const bool lastph = (nt == NT - 1) && ((KT) == 4);                        \
    const int kt1 = ((KT) == 4) ? 0 : ((KT) + 1);                             \
    if (!lastph) { /* B prefetch next phase -> Bs[p^1] */                     \
      const int nt1 = ((KT) == 4) ? nt + 1 : nt;                              \
      const unsigned off =                                                    \
          (unsigned)nt1 * (BN * C_DIM) + (unsigned)(kt1 * 128);               \
      _Pragma("unroll")                                                       \
      for (int j = 0; j < 4; ++j) {                                           \
        const int st = wv * 4 + j;                                            \
        glds16(Sway + (unsigned)st * (8 * 640) + brow + off,                  \
               Bs[p ^ 1] + st * 1024);                                        \
      }                                                                       \
    }                                                                         \
    if ((PRE) && !lastph) {                                                   \
      _Pragma("unroll")                                                       \
      for (int s = 0; s < 4; ++s) {                                           \
        NXT[s]     = *(const i32x4*)(Ar0 + kt1 * 128 + s * 32);               \
        NXT[4 + s] = *(const i32x4*)(Ar1 + kt1 * 128 + s * 32);               \
      }                                                                       \
    }                                                                         \
    const u8* Bp = Bs[p];                                                     \
    _Pragma("unroll")                                                         \
    for (int s = 0; s < 4; ++s) {                                             \
      const i32x4 av0 = CUR[s];                                               \
      const i32x4 av1 = CUR[4 + s];                                           \
      const i32x4 b0v = *(const i32x4*)(Bp + bBase[0] + pqs[s]);              \
      const i32x4 b1v = *(const i32x4*)(Bp + bBase[1] + pqs[s]);              \
      acc[0][0] = __builtin_amdgcn_mfma_i32_32x32x32_i8(av0, b0v, acc[0][0], 0, 0, 0); \
      acc[1][0] = __builtin_amdgcn_mfma_i32_32x32x32_i8(av1, b0v, acc[1][0], 0, 0, 0); \
      acc[0][1] = __builtin_amdgcn_mfma_i32_32x32x32_i8(av0, b1v, acc[0][1], 0, 0, 0); \
      acc[1][1] = __builtin_amdgcn_mfma_i32_32x32x32_i8(av1, b1v, acc[1][1], 0, 0, 0); \
    }                                                                         \
    if (!(PRE) && !lastph) { /* kt==4: self-target aP, must follow MFMAs */   \
      _Pragma("unroll")                                                       \
      for (int s = 0; s < 4; ++s) {                                           \
        NXT[s]     = *(const i32x4*)(Ar0 + kt1 * 128 + s * 32);               \
        NXT[4 + s] = *(const i32x4*)(Ar1 + kt1 * 128 + s * 32);               \
      }                                                                       \
    }                                                                         \
    p ^= 1;                                                                   \
  }

  int p = 0;
  for (int nt = 0; nt < NT; ++nt) {
    PHASE(0, aP, aQ, 1)
    PHASE(1, aQ, aP, 1)
    PHASE(2, aP, aQ, 1)
    PHASE(3, aQ, aP, 1)
    PHASE(4, aP, aP, 0)  // successor is next nt's kt=0, which uses aP

    // end of nt: branchless int top-3 insert (3 ops via med3), re-zero acc.
    // C/D 32x32: col = r5 (-> n), row = (g&3) + 8*(g>>2) + 4*h (+ wm + 32*mi).
    if (nt != NT - 1) {
#pragma unroll
      for (int mi = 0; mi < 2; ++mi)
#pragma unroll
        for (int ni = 0; ni < 2; ++ni)
#pragma unroll
          for (int g = 0; g < 16; ++g) {
            const int v = acc[mi][ni][g];
            const int r = mi * 16 + g;
            t2[r] = med3i(v, t1[r], t2[r]);
            t1[r] = med3i(v, t0[r], t1[r]);
            t0[r] = max(t0[r], v);
            acc[mi][ni][g] = 0;
          }
    } else {                                // last tile: mask pad columns
#pragma unroll
      for (int mi = 0; mi < 2; ++mi)
#pragma unroll
        for (int ni = 0; ni < 2; ++ni) {
          const int ncol = nt * BN + wnB + ni * 32 + r5;
          const bool bad = (ncol >= NWAY);
#pragma unroll
          for (int g = 0; g < 16; ++g) {
            int v = acc[mi][ni][g];
            if (bad) v = NEGINF;
            const int r = mi * 16 + g;
            t2[r] = med3i(v, t1[r], t2[r]);
            t1[r] = med3i(v, t0[r], t1[r]);
            t0[r] = max(t0[r], v);
          }
        }
    }
  }
#undef PHASE

  // ---- partial butterfly over column-lanes d=1,2 (stays in 32-lane half)
#pragma unroll
  for (int d = 1; d <= 2; d <<= 1) {
#pragma unroll
    for (int r = 0; r < 32; ++r) {
      const int o0 = __shfl_xor(t0[r], d);
      const int o1 = __shfl_xor(t1[r], d);
      const int o2 = __shfl_xor(t2[r], d);
      t2[r] = med3i(o0, t1[r], t2[r]);
      t1[r] = med3i(o0, t0[r], t1[r]);
      t0[r] = max(t0[r], o0);
      t2[r] = med3i(o1, t1[r], t2[r]);
      t1[r] = med3i(o1, t0[r], t1[r]);
      t0[r] = max(t0[r], o1);
      t2[r] = med3i(o2, t1[r], t2[r]);
      t1[r] = med3i(o2, t0[r], t1[r]);
      t0[r] = max(t0[r], o2);
    }
  }

  // dump 32 partials/row-slot (2 nh x 8 col-groups = 16 grp) to LDS over Bs.
  // XOR swizzle (row ^ (grp&7)) keeps write/read patterns conflict-light.
  __syncthreads();                          // all B-tile reads complete
  int* part = (int*)&Bs[0][0];              // part[grp][row][4] : 32 KB
  if ((r5 & 3) == 0) {
    const int grp = nh * 8 + (r5 >> 2);     // 0..15
#pragma unroll
    for (int r = 0; r < 32; ++r) {
      const int mi = r >> 4;
      const int g = r & 15;
      const int row_local = wm + mi * 32 + (g & 3) + 8 * (g >> 2) + 4 * h;
      i32x4 v;
      v[0] = t0[r]; v[1] = t1[r]; v[2] = t2[r]; v[3] = NEGINF;
      *(i32x4*)&part[(grp * MCH + (row_local ^ (grp & 7))) * 4] = v;
    }
  }
  __syncthreads();
  if (tid < MCH) {
    const int grow = R0 + tid;
    if (grow < MROWS) {
      int a0_ = NEGINF, a1_ = NEGINF, a2_ = NEGINF;
#pragma unroll 4
      for (int g = 0; g < 16; ++g) {
        const i32x4 v = *(const i32x4*)&part[(g * MCH + (tid ^ (g & 7))) * 4];
        a2_ = med3i(v[0], a1_, a2_); a1_ = med3i(v[0], a0_, a1_); a0_ = max(a0_, v[0]);
        a2_ = med3i(v[1], a1_, a2_); a1_ = med3i(v[1], a0_, a1_); a0_ = max(a0_, v[1]);
        a2_ = med3i(v[2], a1_, a2_); a1_ = med3i(v[2], a0_, a1_); a0_ = max(a0_, v[2]);
      }
      const float rs = (float)(a0_ + a1_ + a2_) * INV_Q2;
      const int qq = grow / HW_DIM;
      atomicAdd(&qsum[qq - (R0 / HW_DIM)], rs);     // block spans <= 2 q's
    }
  }
  __syncthreads();
  if (tid < 2) {
    const int qq = R0 / HW_DIM + tid;
    if (qq < QN) atomicAdd(out + qq * WAYS + way, qsum[tid]);
  }
}

// ---------------------------------------------------------------------------
extern "C" void kernel_launch(void* const* d_in, const int* in_sizes, int n_in,
                              void* d_out, int out_size, void* d_ws, size_t ws_size,
                              hipStream_t stream) {
  const float* x1 = (const float*)d_in[0];
  const float* x2 = (const float*)d_in[1];
  float* out = (float*)d_out;
  u8* A8 = (u8*)d_ws;                                        // MPAD x 640 i8
  u8* S8 = (u8*)d_ws + (size_t)MPAD * C_DIM;                 // 5 x NPAD x 640

  hipLaunchKernelGGL(zero_pad, dim3(1432), dim3(256), 0, stream, A8, S8, out);
  hipLaunchKernelGGL(prep_norm_transpose, dim3(QN * 7), dim3(256), 0, stream,
                     x1, A8, 0);
  hipLaunchKernelGGL(prep_norm_transpose, dim3(SN * 7), dim3(256), 0, stream,
                     x2, S8, 1);
  hipLaunchKernelGGL(simtopk, dim3(WAYS * MBLK), dim3(256), 0, stream,
                     A8, S8, out);
}